// Round 1
// 1410.115 us; speedup vs baseline: 1.0445x; 1.0445x over previous
//
#include <hip/hip_runtime.h>
#include <stdint.h>

#define KK_  1024   // inner dim of both GEMMs

typedef __bf16 bf16x8 __attribute__((ext_vector_type(8)));
typedef float  f32x4  __attribute__((ext_vector_type(4)));
typedef unsigned short u16x8 __attribute__((ext_vector_type(8)));

__device__ __forceinline__ void cp16(void* lds, const void* g) {
  __builtin_amdgcn_global_load_lds(
      (const __attribute__((address_space(1))) void*)g,
      (__attribute__((address_space(3))) void*)lds, 16, 0, 0);
}

__device__ __forceinline__ float b2f(unsigned short u) {
  union { unsigned int i; float f; } x;
  x.i = ((unsigned int)u) << 16;
  return x.f;
}

__device__ __forceinline__ unsigned short f2b(float f) {
  unsigned int u = __builtin_bit_cast(unsigned int, f);
  unsigned int lsb = (u >> 16) & 1u;
  u += 0x7fffu + lsb;
  return (unsigned short)(u >> 16);
}

// fp32 -> bf16 elementwise, 4 elems/thread. n must be a multiple of 4.
__global__ __launch_bounds__(256) void cvt_f32_bf16(
    const float* __restrict__ src, unsigned short* __restrict__ dst, int n) {
  int i = (blockIdx.x * 256 + threadIdx.x) * 4;
  if (i < n) {
    float4 v = *(const float4*)(src + i);
    ushort4 r;
    r.x = f2b(v.x); r.y = f2b(v.y); r.z = f2b(v.z); r.w = f2b(v.w);
    *(ushort4*)(dst + i) = r;
  }
}

// C[m,n] = sum_k A[m,k] * W[n,k] + bias[n]
// A: (M x 1024) bf16 row-major.  W: (N x 1024) bf16 row-major.
// LDS tiles are XOR-swizzled (rule #21 compliant): linear global_load_lds
// dest + inverse-swizzled global SOURCE column + swizzled ds_read address.
// This breaks the 16-way bank conflict of stride-128B fragment reads.
template <bool OUT_F32>
__global__ __launch_bounds__(256) void gemm_bt(
    const unsigned short* __restrict__ A,
    const unsigned short* __restrict__ W0,
    const unsigned short* __restrict__ W1,
    const unsigned short* __restrict__ W2,
    const float* __restrict__ b0,
    const float* __restrict__ b1,
    const float* __restrict__ b2,
    void* __restrict__ Cout,
    int Nout) {
  __shared__ __align__(16) unsigned short sA[128 * 64];
  __shared__ __align__(16) unsigned short sB[128 * 64];

  const int t  = threadIdx.x;
  const int bx = blockIdx.x;
  const int by = blockIdx.y;
  const int wsel = by >> 3;
  const int nloc = (by & 7) * 128;
  const unsigned short* Wm = (wsel == 0) ? W0 : ((wsel == 1) ? W1 : W2);
  const float* bias        = (wsel == 0) ? b0 : ((wsel == 1) ? b1 : b2);

  // staging: thread t loads 8 bf16 (16B); LDS dest = base + t*16B (linear).
  // Source column is pre-swizzled so that the swizzled READ below retrieves
  // logical element (row, col): element (r,c) lives at byte (r*128+2c)^((r&7)<<4).
  const int ar = t >> 3;                                // 0..31 (local row)
  const int ac = ((t & 7) * 8) ^ ((ar & 7) * 8);        // inverse-swizzled col
  const unsigned short* gA = A  + (size_t)(bx * 128 + ar) * KK_ + ac;
  const unsigned short* gB = Wm + (size_t)(nloc + ar) * KK_ + ac;

  const int lane = t & 63;
  const int wv = t >> 6;
  const int wm = (wv >> 1) * 64;
  const int wn = (wv & 1) * 64;
  const int fr = lane & 15;          // fragment row (m or n)
  const int fk = (lane >> 4) * 8;    // fragment k offset
  const int swz = (fr & 7) << 4;     // read-side XOR (matches source swizzle)

  f32x4 zero = {0.f, 0.f, 0.f, 0.f};
  f32x4 acc[4][4];
#pragma unroll
  for (int a = 0; a < 4; ++a)
#pragma unroll
    for (int b = 0; b < 4; ++b) acc[a][b] = zero;

  for (int k0 = 0; k0 < KK_; k0 += 64) {
#pragma unroll
    for (int it = 0; it < 4; ++it) {
      cp16(sA + t * 8 + it * 2048, gA + (size_t)it * 32 * KK_ + k0);
      cp16(sB + t * 8 + it * 2048, gB + (size_t)it * 32 * KK_ + k0);
    }
    __syncthreads();

#pragma unroll
    for (int kk = 0; kk < 64; kk += 32) {
      bf16x8 af[4], bfv[4];
#pragma unroll
      for (int mt = 0; mt < 4; ++mt)
        af[mt] = *(const bf16x8*)((const unsigned char*)sA +
            ((((wm + mt * 16 + fr) * 64 + kk + fk) * 2) ^ swz));
#pragma unroll
      for (int nt = 0; nt < 4; ++nt)
        bfv[nt] = *(const bf16x8*)((const unsigned char*)sB +
            ((((wn + nt * 16 + fr) * 64 + kk + fk) * 2) ^ swz));
#pragma unroll
      for (int mt = 0; mt < 4; ++mt)
#pragma unroll
        for (int nt = 0; nt < 4; ++nt)
          acc[mt][nt] = __builtin_amdgcn_mfma_f32_16x16x32_bf16(
              af[mt], bfv[nt], acc[mt][nt], 0, 0, 0);
    }
    __syncthreads();
  }

  // epilogue: C/D layout col=lane&15, row=(lane>>4)*4+r  [m89-verified]
  const int cc = lane & 15;
  const int rq = (lane >> 4) * 4;
#pragma unroll
  for (int mt = 0; mt < 4; ++mt) {
#pragma unroll
    for (int nt = 0; nt < 4; ++nt) {
      const int gn = by * 128 + wn + nt * 16 + cc;
      const float bb = bias[nloc + wn + nt * 16 + cc];
#pragma unroll
      for (int r = 0; r < 4; ++r) {
        const int gm = bx * 128 + wm + mt * 16 + rq + r;
        const float val = acc[mt][nt][r] + bb;
        if (OUT_F32)
          ((float*)Cout)[(size_t)gm * Nout + gn] = val;
        else
          ((unsigned short*)Cout)[(size_t)gm * Nout + gn] = f2b(val);
      }
    }
  }
}

// One WAVE per (i,j) token pair — no LDS, no barriers.
// energy E'[kh][qh] = mfma(K, Q) (operands swapped so softmax axis qh = C cols
// = lane&15 -> reduce via shfl_xor within 16-lane groups, all lanes active).
// PV (16x16 contraction) in VALU with __shfl gather of the att row.
__global__ __launch_bounds__(256) void attn_wave(
    const unsigned short* __restrict__ qkv,  // (65536, 3072) = [q|k|v] bf16
    unsigned short* __restrict__ ao) {       // (65536, 1024) bf16
  const int lane = threadIdx.x & 63;
  const int p = blockIdx.x * 4 + (threadIdx.x >> 6);
  const int i = p >> 8;
  const int j = p & 255;

  const unsigned short* q = qkv + (size_t)p * 3072;
  const unsigned short* k = qkv + (size_t)(j * 256 + i) * 3072 + 1024;
  const unsigned short* v = q + 2048;

  const int fr = lane & 15;        // qh for B-operand / C col; kh row base via g
  const int g  = lane >> 4;
  const int fk = g * 8;

  // A-frag = K rows (m=kh), B-frag = Q rows (n=qh); both [row=lane&15][k=fk..fk+7]
  const bf16x8 kf0 = *(const bf16x8*)(k + fr * 64 + fk);
  const bf16x8 kf1 = *(const bf16x8*)(k + fr * 64 + 32 + fk);
  const bf16x8 qf0 = *(const bf16x8*)(q + fr * 64 + fk);
  const bf16x8 qf1 = *(const bf16x8*)(q + fr * 64 + 32 + fk);

  f32x4 e = {0.f, 0.f, 0.f, 0.f};
  e = __builtin_amdgcn_mfma_f32_16x16x32_bf16(kf0, qf0, e, 0, 0, 0);
  e = __builtin_amdgcn_mfma_f32_16x16x32_bf16(kf1, qf1, e, 0, 0, 0);
  // lane holds E'[kh = g*4 + r][qh = fr], r = 0..3

  // softmax over qh for each kh row: reduce across the 16 lanes of this group
  float att[4];
#pragma unroll
  for (int r = 0; r < 4; ++r) {
    float m = e[r];
#pragma unroll
    for (int mask = 1; mask <= 8; mask <<= 1)
      m = fmaxf(m, __shfl_xor(m, mask));
    const float pe = __expf(e[r] - m);
    float s = pe;
#pragma unroll
    for (int mask = 1; mask <= 8; mask <<= 1)
      s += __shfl_xor(s, mask);
    att[r] = pe / (32.0f * s);   // post-softmax scale 1/sqrt(1024)
  }

  // PV: lane computes out[qh = fr][dv = g*16 .. g*16+15]
  const int c0 = g * 16;
  float o[16];
#pragma unroll
  for (int u = 0; u < 16; ++u) o[u] = 0.f;

#pragma unroll
  for (int kh = 0; kh < 16; ++kh) {
    // att value (kh, qh=fr) lives in lane fr + (kh>>2)*16, reg kh&3
    const float w = __shfl(att[kh & 3], fr + (kh >> 2) * 16);
    const u16x8 v0 = *(const u16x8*)(v + kh * 64 + c0);
    const u16x8 v1 = *(const u16x8*)(v + kh * 64 + c0 + 8);
#pragma unroll
    for (int u = 0; u < 8; ++u) {
      o[u]     += w * b2f(v0[u]);
      o[8 + u] += w * b2f(v1[u]);
    }
  }

  u16x8 r0, r1;
#pragma unroll
  for (int u = 0; u < 8; ++u) { r0[u] = f2b(o[u]); r1[u] = f2b(o[8 + u]); }
  unsigned short* dst = ao + (size_t)p * 1024 + fr * 64 + c0;
  *(u16x8*)dst       = r0;
  *(u16x8*)(dst + 8) = r1;
}

extern "C" void kernel_launch(void* const* d_in, const int* in_sizes, int n_in,
                              void* d_out, int out_size, void* d_ws, size_t ws_size,
                              hipStream_t stream) {
  const float* x  = (const float*)d_in[0];
  const float* Wq = (const float*)d_in[1];
  const float* bq = (const float*)d_in[2];
  const float* Wk = (const float*)d_in[3];
  const float* bk = (const float*)d_in[4];
  const float* Wv = (const float*)d_in[5];
  const float* bv = (const float*)d_in[6];
  const float* Wp = (const float*)d_in[7];
  const float* bp = (const float*)d_in[8];
  float* out = (float*)d_out;

  // Workspace layout (bf16 = ushort):
  //   qkv     : 65536 x 3072            = 402,653,184 B
  //   ao      : 65536 x 1024            = 134,217,728 B
  //   Wqkv_bf : 3072 x 1024 (q|k|v)     =   6,291,456 B
  //   Wp_bf   : 1024 x 1024             =   2,097,152 B   (total ~545 MB)
  unsigned short* qkv     = (unsigned short*)d_ws;
  unsigned short* ao      = qkv + (size_t)65536 * 3072;
  unsigned short* Wqkv_bf = ao  + (size_t)65536 * 1024;
  unsigned short* Wp_bf   = Wqkv_bf + (size_t)3072 * 1024;
  // x_bf16 (134 MB) lives in d_out (268 MB fp32); overwritten by final GEMM.
  unsigned short* x_bf = (unsigned short*)d_out;

  const int NX = 65536 * 1024;  // x elements
  const int NW = 1024 * 1024;   // one weight matrix

  cvt_f32_bf16<<<NX / 1024, 256, 0, stream>>>(x, x_bf, NX);
  cvt_f32_bf16<<<NW / 1024, 256, 0, stream>>>(Wq, Wqkv_bf, NW);
  cvt_f32_bf16<<<NW / 1024, 256, 0, stream>>>(Wk, Wqkv_bf + (size_t)NW, NW);
  cvt_f32_bf16<<<NW / 1024, 256, 0, stream>>>(Wv, Wqkv_bf + (size_t)2 * NW, NW);
  cvt_f32_bf16<<<NW / 1024, 256, 0, stream>>>(Wp, Wp_bf, NW);

  // fused QKV projection: (65536x1024) @ [Wq;Wk;Wv]^T -> qkv (65536x3072) bf16
  gemm_bt<false><<<dim3(512, 24), dim3(256), 0, stream>>>(
      x_bf, Wqkv_bf, Wqkv_bf + (size_t)NW, Wqkv_bf + (size_t)2 * NW,
      bq, bk, bv, (void*)qkv, 3072);
  // per-pair head-vs-head attention: one wave per pair
  attn_wave<<<dim3(65536 / 4), dim3(256), 0, stream>>>(qkv, ao);
  // output projection: (65536x1024) @ Wp^T -> d_out (fp32)
  gemm_bt<true><<<dim3(512, 8), dim3(256), 0, stream>>>(
      ao, Wp_bf, Wp_bf, Wp_bf, bp, bp, bp, (void*)out, 1024);
}